// Round 7
// baseline (190.642 us; speedup 1.0000x reference)
//
#include <hip/hip_runtime.h>
#include <hip/hip_bf16.h>
#include <stdint.h>

typedef __attribute__((ext_vector_type(8))) short short8;
typedef __attribute__((ext_vector_type(4))) float f32x4;

#define NTHREADS 256
#define DIM 128
#define NH 16
#define HD 8
#define HIDDEN 344
#define HIDP 352          // HIDDEN padded to multiple of 32
#define BATCH 4
#define SEQ 2048
#define MROWS (BATCH * SEQ)   // 8192
#define LOG2E 1.4426950408889634f

static __device__ __forceinline__ uint16_t f2bf(float f) {
  union { float f; uint32_t u; } v; v.f = f;
  uint32_t r = v.u + 0x7FFFu + ((v.u >> 16) & 1u);
  return (uint16_t)(r >> 16);
}
static __device__ __forceinline__ float fast_exp2(float x) {
#if __has_builtin(__builtin_amdgcn_exp2f)
  return __builtin_amdgcn_exp2f(x);
#else
  return exp2f(x);
#endif
}
// RNE pack: compiler emits v_cvt_pk_bf16_f32
static __device__ __forceinline__ uint32_t pk2(float lo, float hi) {
  union { __hip_bfloat162 b; uint32_t u; } c;
  c.b = __float22bfloat162_rn(make_float2(lo, hi));
  return c.u;
}
// truncating bf16x2 pack: one v_perm_b32 (p >= 0, error <= 2^-8 relative)
static __device__ __forceinline__ uint32_t pkt(float lo, float hi) {
  return __builtin_amdgcn_perm(__builtin_bit_cast(uint32_t, hi),
                               __builtin_bit_cast(uint32_t, lo), 0x07060302u);
}
static __device__ __forceinline__ f32x4 mfma32(short8 a, short8 b, f32x4 c) {
  return __builtin_amdgcn_mfma_f32_16x16x32_bf16(a, b, c, 0, 0, 0);
}

// ------------------------------------------------------------------
// prep: weights -> transposed bf16 Wt[n][k], padded where needed.
// wq rows pre-scaled by log2(e) so attention uses exp2 directly.
// w1t/w3t padded to 384 rows (zeros), w2t padded to 352 k (zeros).
// ------------------------------------------------------------------
__global__ __launch_bounds__(256) void prep_kernel(
    const float* __restrict__ wq,
    const float* __restrict__ wk, const float* __restrict__ wv,
    const float* __restrict__ wo, const float* __restrict__ w1,
    const float* __restrict__ w3, const float* __restrict__ w2,
    uint16_t* __restrict__ qkv_t,
    uint16_t* __restrict__ wo_t,  uint16_t* __restrict__ w1_t,
    uint16_t* __restrict__ w3_t,  uint16_t* __restrict__ w2_t)
{
  const int nt  = gridDim.x * blockDim.x;
  const int tid = blockIdx.x * blockDim.x + threadIdx.x;
  for (int i = tid; i < 384 * 128; i += nt) {
    int n = i >> 7, k = i & 127;
    const float* w = (n < 128) ? wq : ((n < 256) ? wk : wv);
    const float s = (n < 128) ? LOG2E : 1.0f;
    qkv_t[i] = f2bf(w[k * 128 + (n & 127)] * s);
  }
  for (int i = tid; i < 128 * 128; i += nt) {
    int n = i >> 7, k = i & 127;
    wo_t[i] = f2bf(wo[k * 128 + n]);
  }
  for (int i = tid; i < 384 * 128; i += nt) {
    int n = i >> 7, k = i & 127;
    w1_t[i] = (n < HIDDEN) ? f2bf(w1[k * HIDDEN + n]) : (uint16_t)0;
    w3_t[i] = (n < HIDDEN) ? f2bf(w3[k * HIDDEN + n]) : (uint16_t)0;
  }
  for (int i = tid; i < 128 * HIDP; i += nt) {
    int n = i / HIDP, k = i - n * HIDP;
    w2_t[i] = (k < HIDDEN) ? f2bf(w2[k * 128 + n]) : (uint16_t)0;
  }
}

// ------------------------------------------------------------------
// Register-streaming GEMM: no LDS, no barriers. Block = 4 waves; wave
// computes 16 rows x 64 cols. A-frag: lane(lg,lm) = A[row0+lm][8lg+32ks..]
// (contiguous short8). B-frag: lane = Bt[col][8lg+32ks..]. KT compile-time.
// EPI 0: QKV writer: col<128 -> q_buf; 128..255 -> Kc[b,h][s][8];
//        256..383 -> Vt[b,h*8+d][s]
// EPI 1: h = acc + addf; outb=bf16(h), outf=h
// EPI 2: u = silu(acc1) * acc2 -> outb[.][HIDP] (zeros in pad cols)
// EPI 3: outf += acc
// ------------------------------------------------------------------
template <int EPI, int KT, bool AF32>
__global__ __launch_bounds__(256, 4) void rsgemm(
    const void* __restrict__ Av,     const uint16_t* __restrict__ B1t,
    const uint16_t* __restrict__ B2t,
    uint16_t* __restrict__ outb, float* __restrict__ outf,
    const float* __restrict__ addf,
    uint16_t* __restrict__ kc_o, uint16_t* __restrict__ vt_o)
{
  constexpr int NKS = KT / 32;
  const int tid = threadIdx.x;
  const int w = tid >> 6, l = tid & 63;
  const int lg = l >> 4, lm = l & 15;
  const int row0 = blockIdx.x * 64 + w * 16;
  const int col0 = blockIdx.y * 64;

  // ---- A fragments (held for all 4 col-tiles) ----
  short8 af[NKS];
  if constexpr (AF32) {
    const float* Af = (const float*)Av + (size_t)(row0 + lm) * KT + lg * 8;
#pragma unroll
    for (int ks = 0; ks < NKS; ++ks) {
      const f32x4 a0 = *(const f32x4*)(Af + ks * 32);
      const f32x4 a1 = *(const f32x4*)(Af + ks * 32 + 4);
      union { uint32_t u[4]; short8 s8; } cv;
      cv.u[0] = pk2(a0[0], a0[1]); cv.u[1] = pk2(a0[2], a0[3]);
      cv.u[2] = pk2(a1[0], a1[1]); cv.u[3] = pk2(a1[2], a1[3]);
      af[ks] = cv.s8;
    }
  } else {
    const uint16_t* Ab = (const uint16_t*)Av + (size_t)(row0 + lm) * KT + lg * 8;
#pragma unroll
    for (int ks = 0; ks < NKS; ++ks) af[ks] = *(const short8*)(Ab + ks * 32);
  }

  f32x4 acc[4], acc2[4];
#pragma unroll
  for (int t = 0; t < 4; ++t) {
    acc[t] = (f32x4){0.f, 0.f, 0.f, 0.f};
    acc2[t] = (f32x4){0.f, 0.f, 0.f, 0.f};
  }

#pragma unroll
  for (int t = 0; t < 4; ++t) {
    const uint16_t* Bp = B1t + (size_t)(col0 + t * 16 + lm) * KT + lg * 8;
#pragma unroll
    for (int ks = 0; ks < NKS; ++ks)
      acc[t] = mfma32(af[ks], *(const short8*)(Bp + ks * 32), acc[t]);
    if constexpr (EPI == 2) {
      const uint16_t* B2p = B2t + (size_t)(col0 + t * 16 + lm) * KT + lg * 8;
#pragma unroll
      for (int ks = 0; ks < NKS; ++ks)
        acc2[t] = mfma32(af[ks], *(const short8*)(B2p + ks * 32), acc2[t]);
    }
  }

  // ---- epilogue: D layout col=lm (t*16), row=lg*4+r ----
#pragma unroll
  for (int t = 0; t < 4; ++t) {
#pragma unroll
    for (int r = 0; r < 4; ++r) {
      const int row = row0 + lg * 4 + r;
      const int col = col0 + t * 16 + lm;
      const float v = acc[t][r];
      if constexpr (EPI == 0) {
        const int bb = row >> 11, ss = row & 2047;
        if (col < 128) {
          outb[(size_t)row * 128 + col] = f2bf(v);          // Q (pre-scaled)
        } else if (col < 256) {
          const int c = col - 128;
          kc_o[((size_t)((bb << 4) + (c >> 3)) * SEQ + ss) * 8 + (c & 7)] = f2bf(v);
        } else {
          const int c = col - 256;
          vt_o[((size_t)(bb * 128 + c)) * SEQ + ss] = f2bf(v);
        }
      } else if constexpr (EPI == 1) {
        const float h = v + addf[(size_t)row * DIM + col];
        outb[(size_t)row * DIM + col] = f2bf(h);
        outf[(size_t)row * DIM + col] = h;
      } else if constexpr (EPI == 2) {
        if (col < HIDDEN) {
          const float g = v, e = acc2[t][r];
          const float u = g / (1.f + __expf(-g)) * e;
          outb[(size_t)row * HIDP + col] = f2bf(u);
        } else if (col < HIDP) {
          outb[(size_t)row * HIDP + col] = 0;
        }
      } else {
        outf[(size_t)row * DIM + col] += v;
      }
    }
  }
}

// ------------------------------------------------------------------
// Flash attention: block = (b, h, 32 q rows); 4 waves each take a
// quarter of the keys (512) for the SAME 32 q rows (2 tiles of 16).
// No-max softmax => partial accumulators merge by pure addition (LDS).
// QK^T swapped (mfma 16x16x32), permuted K rows so the QK D-layout IS
// the PV B-fragment layout. p = exp2(score). PV A = Vt rows on lm;
// lm==8 carries a ones-row -> acc row 8 = sum(p). Double-buffered
// named registers, loads for chunk i+1 before compute of chunk i.
// ------------------------------------------------------------------
__global__ __launch_bounds__(256, 6) void attn_kernel(
    const uint16_t* __restrict__ qb,   // [MROWS][128]  (pre-scaled Q)
    const uint16_t* __restrict__ kc,   // [B*NH][SEQ][8]
    const uint16_t* __restrict__ vt,   // [B*NH*8][SEQ]
    uint16_t* __restrict__ attn_o)     // [MROWS][128]
{
  __shared__ __attribute__((aligned(16))) float part[4][64][8];

  const int tid = threadIdx.x;
  const int w = tid >> 6, l = tid & 63;
  const int lg = l >> 4, lm = l & 15;
  int bid = blockIdx.x;
  bid = (bid & 7) * 512 + (bid >> 3);   // bijective XCD swizzle (4096 % 8 == 0)
  const int qc = bid & 63;              // SEQ/32 = 64 q-chunks
  const int bh = bid >> 6;
  const int b = bh >> 4, h = bh & 15;
  const int q0 = qc * 32;

  const short8 zero8 = {0, 0, 0, 0, 0, 0, 0, 0};
  const f32x4 zero4 = {0.f, 0.f, 0.f, 0.f};
  const short ob = (short)0x3F80;  // bf16 1.0
  const short8 ones8 = {ob, ob, ob, ob, ob, ob, ob, ob};

  // Q fragments (once): B-frag lanes lg==0 hold Q[q][d=0..7]
  short8 qf0 = zero8, qf1 = zero8;
  if (lg == 0) {
    qf0 = *(const short8*)(qb + (size_t)(b * SEQ + q0 + lm) * DIM + h * HD);
    qf1 = *(const short8*)(qb + (size_t)(b * SEQ + q0 + 16 + lm) * DIM + h * HD);
  }

  // wave w owns keys [w*512, w*512+512): 8 chunks of 64
  // permuted K base: tile-A row lm <- key 8*(lm>>2)+(lm&3)
  const uint16_t* kp = kc + (size_t)bh * SEQ * HD +
                       (w * 512 + 8 * (lm >> 2) + (lm & 3)) * HD;
  // V: A-frag lane (lg, lm<8) holds Vt[d=lm][key + 8*lg + j]
  const uint16_t* vp = vt + (size_t)(bh * HD + (lm & 7)) * SEQ + w * 512 + lg * 8;

  // named K/V double buffers
  short8 ka0 = zero8, ka1 = zero8, ka2 = zero8, ka3 = zero8;
  short8 kb0 = zero8, kb1 = zero8, kb2 = zero8, kb3 = zero8;
  const short8 vinit = (lm == 8) ? ones8 : zero8;
  short8 va0 = vinit, va1 = vinit, vb0 = vinit, vb1 = vinit;

  f32x4 o00 = zero4, o01 = zero4, o10 = zero4, o11 = zero4;

#define LK(R0, R1, R2, R3)                         \
  do { if (lg == 0) {                              \
    R0 = *(const short8*)(kp);                     \
    R1 = *(const short8*)(kp + 32);                \
    R2 = *(const short8*)(kp + 256);               \
    R3 = *(const short8*)(kp + 288); }             \
    kp += 512; } while (0)

#define LV(R0, R1)                                 \
  do { if (lm < HD) {                              \
    R0 = *(const short8*)(vp);                     \
    R1 = *(const short8*)(vp + 32); }              \
    vp += 64; } while (0)

#define PACKP(SA, SB, OUT)                                  \
  do { union { uint32_t u[4]; short8 s; } _t;               \
    _t.u[0] = pkt(fast_exp2(SA[0]), fast_exp2(SA[1]));      \
    _t.u[1] = pkt(fast_exp2(SA[2]), fast_exp2(SA[3]));      \
    _t.u[2] = pkt(fast_exp2(SB[0]), fast_exp2(SB[1]));      \
    _t.u[3] = pkt(fast_exp2(SB[2]), fast_exp2(SB[3]));      \
    OUT = _t.s; } while (0)

#define COMPUTE(K0, K1, K2, K3, V0, V1)                     \
  do {                                                      \
    f32x4 s0, s1, s2, s3, s4, s5, s6, s7;                   \
    __builtin_amdgcn_s_setprio(1);                          \
    s0 = mfma32(K0, qf0, zero4);                            \
    s1 = mfma32(K1, qf0, zero4);                            \
    s2 = mfma32(K2, qf0, zero4);                            \
    s3 = mfma32(K3, qf0, zero4);                            \
    s4 = mfma32(K0, qf1, zero4);                            \
    s5 = mfma32(K1, qf1, zero4);                            \
    s6 = mfma32(K2, qf1, zero4);                            \
    s7 = mfma32(K3, qf1, zero4);                            \
    __builtin_amdgcn_s_setprio(0);                          \
    short8 p0, p1, p2, p3;                                  \
    PACKP(s0, s1, p0);                                      \
    PACKP(s2, s3, p1);                                      \
    PACKP(s4, s5, p2);                                      \
    PACKP(s6, s7, p3);                                      \
    __builtin_amdgcn_s_setprio(1);                          \
    o00 = mfma32(V0, p0, o00);                              \
    o01 = mfma32(V1, p1, o01);                              \
    o10 = mfma32(V0, p2, o10);                              \
    o11 = mfma32(V1, p3, o11);                              \
    __builtin_amdgcn_s_setprio(0);                          \
  } while (0)

  // software pipeline over 8 chunks of 64 keys
  LK(ka0, ka1, ka2, ka3); LV(va0, va1);
#pragma unroll 1
  for (int it = 0; it < 3; ++it) {
    LK(kb0, kb1, kb2, kb3); LV(vb0, vb1);
    COMPUTE(ka0, ka1, ka2, ka3, va0, va1);
    LK(ka0, ka1, ka2, ka3); LV(va0, va1);
    COMPUTE(kb0, kb1, kb2, kb3, vb0, vb1);
  }
  LK(kb0, kb1, kb2, kb3); LV(vb0, vb1);
  COMPUTE(ka0, ka1, ka2, ka3, va0, va1);
  COMPUTE(kb0, kb1, kb2, kb3, vb0, vb1);

#undef LK
#undef LV
#undef PACKP
#undef COMPUTE

  // ---- merge partials across the 4 key-quarters ----
  const f32x4 accA = o00 + o01;   // tile 0 (rows q0 + lm)
  const f32x4 accB = o10 + o11;   // tile 1 (rows q0 + 16 + lm)
  *(f32x4*)&part[w][l][0] = accA;
  *(f32x4*)&part[w][l][4] = accB;
  __syncthreads();

  if (w < 2) {   // wave0 -> tile A, wave1 -> tile B
    f32x4 m = (f32x4){0.f, 0.f, 0.f, 0.f};
#pragma unroll
    for (int ww = 0; ww < 4; ++ww) m += *(const f32x4*)&part[ww][l][w * 4];
    // row 8 (lane 32+lm, reg 0) holds sum(p) for q=lm
    const float inv = 1.0f / __shfl(m[0], 32 + lm);
    if (lg < 2) {
      const size_t o = (size_t)(b * SEQ + q0 + w * 16 + lm) * DIM + h * HD + lg * 4;
      *(uint32_t*)(attn_o + o)     = pk2(m[0] * inv, m[1] * inv);
      *(uint32_t*)(attn_o + o + 2) = pk2(m[2] * inv, m[3] * inv);
    }
  }
}

// ------------------------------------------------------------------
extern "C" void kernel_launch(void* const* d_in, const int* in_sizes, int n_in,
                              void* d_out, int out_size, void* d_ws, size_t ws_size,
                              hipStream_t stream) {
  const float* x  = (const float*)d_in[0];
  const float* wq = (const float*)d_in[1];
  const float* wk = (const float*)d_in[2];
  const float* wv = (const float*)d_in[3];
  const float* wo = (const float*)d_in[4];
  const float* w1 = (const float*)d_in[5];
  const float* w3 = (const float*)d_in[6];
  const float* w2 = (const float*)d_in[7];
  float* out = (float*)d_out;

  char* ws = (char*)d_ws;
  size_t off = 0;
  auto alloc = [&](size_t bytes) {
    size_t o = off;
    off += (bytes + 255) & ~(size_t)255;
    return o;
  };
  uint16_t* qkv_t  = (uint16_t*)(ws + alloc(384 * 128 * 2));
  uint16_t* wo_t   = (uint16_t*)(ws + alloc(128 * 128 * 2));
  uint16_t* w1_t   = (uint16_t*)(ws + alloc(384 * 128 * 2));
  uint16_t* w3_t   = (uint16_t*)(ws + alloc(384 * 128 * 2));
  uint16_t* w2_t   = (uint16_t*)(ws + alloc(128 * HIDP * 2));
  uint16_t* q_buf  = (uint16_t*)(ws + alloc((size_t)MROWS * DIM * 2));
  uint16_t* kc_b   = (uint16_t*)(ws + alloc((size_t)MROWS * DIM * 2));
  uint16_t* vt_b   = (uint16_t*)(ws + alloc((size_t)MROWS * DIM * 2));
  uint16_t* attn_o = (uint16_t*)(ws + alloc((size_t)MROWS * DIM * 2));
  uint16_t* h_bf   = (uint16_t*)(ws + alloc((size_t)MROWS * DIM * 2));
  uint16_t* u_buf  = (uint16_t*)(ws + alloc((size_t)MROWS * HIDP * 2));

  prep_kernel<<<512, 256, 0, stream>>>(wq, wk, wv, wo, w1, w3, w2,
                                       qkv_t, wo_t, w1_t, w3_t, w2_t);
  // qkv = x @ [wq*log2e | wk | wv] -> q_buf, Kc, Vt  (A read as fp32)
  rsgemm<0, 128, true><<<dim3(MROWS / 64, 6), 256, 0, stream>>>(
      x, qkv_t, nullptr, q_buf, nullptr, nullptr, kc_b, vt_b);
  // flash attention: 4096 blocks, 4-way key split per block
  attn_kernel<<<dim3(BATCH * NH * (SEQ / 32)), 256, 0, stream>>>(
      q_buf, kc_b, vt_b, attn_o);
  // h = x + attn @ wo
  rsgemm<1, 128, false><<<dim3(MROWS / 64, 2), 256, 0, stream>>>(
      attn_o, wo_t, nullptr, h_bf, out, x, nullptr, nullptr);
  // u = silu(h@w1) * (h@w3)   (cols padded to 352 with zeros)
  rsgemm<2, 128, false><<<dim3(MROWS / 64, 6), 256, 0, stream>>>(
      h_bf, w1_t, w3_t, u_buf, nullptr, nullptr, nullptr, nullptr);
  // out += u @ w2
  rsgemm<3, HIDP, false><<<dim3(MROWS / 64, 2), 256, 0, stream>>>(
      u_buf, w2_t, nullptr, nullptr, out, nullptr, nullptr, nullptr);
}

// Round 8
// 87.634 us; speedup vs baseline: 2.1754x; 2.1754x over previous
//
#include <hip/hip_runtime.h>
#include <hip/hip_bf16.h>
#include <stdint.h>

typedef __attribute__((ext_vector_type(8))) short short8;
typedef __attribute__((ext_vector_type(4))) float f32x4;

#define NTHREADS 256
#define DIM 128
#define NH 16
#define HD 8
#define HIDDEN 344
#define HIDP 352          // HIDDEN padded to multiple of 32
#define BATCH 4
#define SEQ 2048
#define MROWS (BATCH * SEQ)   // 8192
#define LOG2E 1.4426950408889634f

static __device__ __forceinline__ uint16_t f2bf(float f) {
  union { float f; uint32_t u; } v; v.f = f;
  uint32_t r = v.u + 0x7FFFu + ((v.u >> 16) & 1u);
  return (uint16_t)(r >> 16);
}
static __device__ __forceinline__ float fast_exp2(float x) {
#if __has_builtin(__builtin_amdgcn_exp2f)
  return __builtin_amdgcn_exp2f(x);
#else
  return exp2f(x);
#endif
}
// RNE pack: compiler emits v_cvt_pk_bf16_f32
static __device__ __forceinline__ uint32_t pk2(float lo, float hi) {
  union { __hip_bfloat162 b; uint32_t u; } c;
  c.b = __float22bfloat162_rn(make_float2(lo, hi));
  return c.u;
}
// truncating bf16x2 pack: one v_perm_b32 (p >= 0, error <= 2^-8 relative)
static __device__ __forceinline__ uint32_t pkt(float lo, float hi) {
  return __builtin_amdgcn_perm(__builtin_bit_cast(uint32_t, hi),
                               __builtin_bit_cast(uint32_t, lo), 0x07060302u);
}
static __device__ __forceinline__ f32x4 mfma32(short8 a, short8 b, f32x4 c) {
  return __builtin_amdgcn_mfma_f32_16x16x32_bf16(a, b, c, 0, 0, 0);
}

// ------------------------------------------------------------------
// prep: weights -> transposed bf16 Wt[n][k], padded where needed.
// wq rows pre-scaled by log2(e) so attention uses exp2 directly.
// w1t/w3t padded to 384 rows (zeros), w2t padded to 352 k (zeros).
// ------------------------------------------------------------------
__global__ __launch_bounds__(256) void prep_kernel(
    const float* __restrict__ wq,
    const float* __restrict__ wk, const float* __restrict__ wv,
    const float* __restrict__ wo, const float* __restrict__ w1,
    const float* __restrict__ w3, const float* __restrict__ w2,
    uint16_t* __restrict__ qkv_t,
    uint16_t* __restrict__ wo_t,  uint16_t* __restrict__ w1_t,
    uint16_t* __restrict__ w3_t,  uint16_t* __restrict__ w2_t)
{
  const int nt  = gridDim.x * blockDim.x;
  const int tid = blockIdx.x * blockDim.x + threadIdx.x;
  for (int i = tid; i < 384 * 128; i += nt) {
    int n = i >> 7, k = i & 127;
    const float* w = (n < 128) ? wq : ((n < 256) ? wk : wv);
    const float s = (n < 128) ? LOG2E : 1.0f;
    qkv_t[i] = f2bf(w[k * 128 + (n & 127)] * s);
  }
  for (int i = tid; i < 128 * 128; i += nt) {
    int n = i >> 7, k = i & 127;
    wo_t[i] = f2bf(wo[k * 128 + n]);
  }
  for (int i = tid; i < 384 * 128; i += nt) {
    int n = i >> 7, k = i & 127;
    w1_t[i] = (n < HIDDEN) ? f2bf(w1[k * HIDDEN + n]) : (uint16_t)0;
    w3_t[i] = (n < HIDDEN) ? f2bf(w3[k * HIDDEN + n]) : (uint16_t)0;
  }
  for (int i = tid; i < 128 * HIDP; i += nt) {
    int n = i / HIDP, k = i - n * HIDP;
    w2_t[i] = (k < HIDDEN) ? f2bf(w2[k * 128 + n]) : (uint16_t)0;
  }
}

// ------------------------------------------------------------------
// Register-streaming GEMM: no LDS, no barriers. Block = 4 waves; wave
// computes 16 rows x 64 cols. A-frag: lane(lg,lm) = A[row0+lm][8lg+32ks..]
// (contiguous short8). B-frag: lane = Bt[col][8lg+32ks..]. KT compile-time.
// EPI 0: QKV writer: col<128 -> q_buf; 128..255 -> Kc[b,h][s][8];
//        256..383 -> Vt[b,h*8+d][s]
// EPI 1: h = acc + addf; outb=bf16(h), outf=h
// EPI 2: u = silu(acc1) * acc2 -> outb[.][HIDP] (zeros in pad cols)
// EPI 3: outf += acc
// ------------------------------------------------------------------
template <int EPI, int KT, bool AF32>
__global__ __launch_bounds__(256, 4) void rsgemm(
    const void* __restrict__ Av,     const uint16_t* __restrict__ B1t,
    const uint16_t* __restrict__ B2t,
    uint16_t* __restrict__ outb, float* __restrict__ outf,
    const float* __restrict__ addf,
    uint16_t* __restrict__ kc_o, uint16_t* __restrict__ vt_o)
{
  constexpr int NKS = KT / 32;
  const int tid = threadIdx.x;
  const int w = tid >> 6, l = tid & 63;
  const int lg = l >> 4, lm = l & 15;
  const int row0 = blockIdx.x * 64 + w * 16;
  const int col0 = blockIdx.y * 64;

  // ---- A fragments (held for all 4 col-tiles) ----
  short8 af[NKS];
  if constexpr (AF32) {
    const float* Af = (const float*)Av + (size_t)(row0 + lm) * KT + lg * 8;
#pragma unroll
    for (int ks = 0; ks < NKS; ++ks) {
      const f32x4 a0 = *(const f32x4*)(Af + ks * 32);
      const f32x4 a1 = *(const f32x4*)(Af + ks * 32 + 4);
      union { uint32_t u[4]; short8 s8; } cv;
      cv.u[0] = pk2(a0[0], a0[1]); cv.u[1] = pk2(a0[2], a0[3]);
      cv.u[2] = pk2(a1[0], a1[1]); cv.u[3] = pk2(a1[2], a1[3]);
      af[ks] = cv.s8;
    }
  } else {
    const uint16_t* Ab = (const uint16_t*)Av + (size_t)(row0 + lm) * KT + lg * 8;
#pragma unroll
    for (int ks = 0; ks < NKS; ++ks) af[ks] = *(const short8*)(Ab + ks * 32);
  }

  f32x4 acc[4], acc2[4];
#pragma unroll
  for (int t = 0; t < 4; ++t) {
    acc[t] = (f32x4){0.f, 0.f, 0.f, 0.f};
    acc2[t] = (f32x4){0.f, 0.f, 0.f, 0.f};
  }

#pragma unroll
  for (int t = 0; t < 4; ++t) {
    const uint16_t* Bp = B1t + (size_t)(col0 + t * 16 + lm) * KT + lg * 8;
#pragma unroll
    for (int ks = 0; ks < NKS; ++ks)
      acc[t] = mfma32(af[ks], *(const short8*)(Bp + ks * 32), acc[t]);
    if constexpr (EPI == 2) {
      const uint16_t* B2p = B2t + (size_t)(col0 + t * 16 + lm) * KT + lg * 8;
#pragma unroll
      for (int ks = 0; ks < NKS; ++ks)
        acc2[t] = mfma32(af[ks], *(const short8*)(B2p + ks * 32), acc2[t]);
    }
  }

  // ---- epilogue: D layout col=lm (t*16), row=lg*4+r ----
#pragma unroll
  for (int t = 0; t < 4; ++t) {
#pragma unroll
    for (int r = 0; r < 4; ++r) {
      const int row = row0 + lg * 4 + r;
      const int col = col0 + t * 16 + lm;
      const float v = acc[t][r];
      if constexpr (EPI == 0) {
        const int bb = row >> 11, ss = row & 2047;
        if (col < 128) {
          outb[(size_t)row * 128 + col] = f2bf(v);          // Q (pre-scaled)
        } else if (col < 256) {
          const int c = col - 128;
          kc_o[((size_t)((bb << 4) + (c >> 3)) * SEQ + ss) * 8 + (c & 7)] = f2bf(v);
        } else {
          const int c = col - 256;
          vt_o[((size_t)(bb * 128 + c)) * SEQ + ss] = f2bf(v);
        }
      } else if constexpr (EPI == 1) {
        const float h = v + addf[(size_t)row * DIM + col];
        outb[(size_t)row * DIM + col] = f2bf(h);
        outf[(size_t)row * DIM + col] = h;
      } else if constexpr (EPI == 2) {
        if (col < HIDDEN) {
          const float g = v, e = acc2[t][r];
          const float u = g / (1.f + __expf(-g)) * e;
          outb[(size_t)row * HIDP + col] = f2bf(u);
        } else if (col < HIDP) {
          outb[(size_t)row * HIDP + col] = 0;
        }
      } else {
        outf[(size_t)row * DIM + col] += v;
      }
    }
  }
}

// ------------------------------------------------------------------
// Flash attention (r5-proven): no LDS, no barriers. Block = (b, h, 128
// q rows); 4 waves x 32 q rows (2 tiles of 16). Fully named registers,
// K/V double-buffered, loads for chunk i+1 issued before compute of i.
// QK^T swapped (mfma 16x16x32), permuted K rows so the QK D-layout IS
// the PV B-fragment layout. p = exp2(score), no max subtraction.
// PV A = Vt rows on lm; lm==8 carries a ones-row -> acc row 8 = sum(p).
// NOTE: needs ~60 VGPRs; only (256,4) leaves the working set intact
// (r6's (256,8) and r7's (256,6) both forced spills -- do not repeat).
// ------------------------------------------------------------------
__global__ __launch_bounds__(256, 4) void attn_kernel(
    const uint16_t* __restrict__ qb,   // [MROWS][128]  (pre-scaled Q)
    const uint16_t* __restrict__ kc,   // [B*NH][SEQ][8]
    const uint16_t* __restrict__ vt,   // [B*NH*8][SEQ]
    uint16_t* __restrict__ attn_o)     // [MROWS][128]
{
  const int tid = threadIdx.x;
  const int w = tid >> 6, l = tid & 63;
  const int lg = l >> 4, lm = l & 15;
  int bid = blockIdx.x;
  bid = (bid & 7) * 128 + (bid >> 3);   // bijective XCD swizzle (1024 % 8 == 0)
  const int qc = bid & 15;              // SEQ/128 = 16 q-chunks
  const int bh = bid >> 4;
  const int b = bh >> 4, h = bh & 15;
  const int q0 = qc * 128 + w * 32;

  const short8 zero8 = {0, 0, 0, 0, 0, 0, 0, 0};
  const f32x4 zero4 = {0.f, 0.f, 0.f, 0.f};
  const short ob = (short)0x3F80;  // bf16 1.0
  const short8 ones8 = {ob, ob, ob, ob, ob, ob, ob, ob};

  // Q fragments (once): B-frag lanes lg==0 hold Q[q][d=0..7]
  short8 qf0 = zero8, qf1 = zero8;
  if (lg == 0) {
    qf0 = *(const short8*)(qb + (size_t)(b * SEQ + q0 + lm) * DIM + h * HD);
    qf1 = *(const short8*)(qb + (size_t)(b * SEQ + q0 + 16 + lm) * DIM + h * HD);
  }

  // permuted K base: tile-A row lm <- key 8*(lm>>2)+(lm&3)
  const uint16_t* kp = kc + (size_t)bh * SEQ * HD + (8 * (lm >> 2) + (lm & 3)) * HD;
  // V: A-frag lane (lg, lm<8) holds Vt[d=lm][key kb + 8*lg + j]
  const uint16_t* vp = vt + (size_t)(bh * HD + (lm & 7)) * SEQ + lg * 8;

  // named K/V double buffers
  short8 ka0 = zero8, ka1 = zero8, ka2 = zero8, ka3 = zero8;
  short8 kb0 = zero8, kb1 = zero8, kb2 = zero8, kb3 = zero8;
  const short8 vinit = (lm == 8) ? ones8 : zero8;
  short8 va0 = vinit, va1 = vinit, vb0 = vinit, vb1 = vinit;

  f32x4 o00 = zero4, o01 = zero4, o10 = zero4, o11 = zero4;

#define LK(R0, R1, R2, R3)                         \
  do { if (lg == 0) {                              \
    R0 = *(const short8*)(kp);                     \
    R1 = *(const short8*)(kp + 32);                \
    R2 = *(const short8*)(kp + 256);               \
    R3 = *(const short8*)(kp + 288); }             \
    kp += 512; } while (0)

#define LV(R0, R1)                                 \
  do { if (lm < HD) {                              \
    R0 = *(const short8*)(vp);                     \
    R1 = *(const short8*)(vp + 32); }              \
    vp += 64; } while (0)

#define PACKP(SA, SB, OUT)                                  \
  do { union { uint32_t u[4]; short8 s; } _t;               \
    _t.u[0] = pkt(fast_exp2(SA[0]), fast_exp2(SA[1]));      \
    _t.u[1] = pkt(fast_exp2(SA[2]), fast_exp2(SA[3]));      \
    _t.u[2] = pkt(fast_exp2(SB[0]), fast_exp2(SB[1]));      \
    _t.u[3] = pkt(fast_exp2(SB[2]), fast_exp2(SB[3]));      \
    OUT = _t.s; } while (0)

#define COMPUTE(K0, K1, K2, K3, V0, V1)                     \
  do {                                                      \
    f32x4 s0, s1, s2, s3, s4, s5, s6, s7;                   \
    __builtin_amdgcn_s_setprio(1);                          \
    s0 = mfma32(K0, qf0, zero4);                            \
    s1 = mfma32(K1, qf0, zero4);                            \
    s2 = mfma32(K2, qf0, zero4);                            \
    s3 = mfma32(K3, qf0, zero4);                            \
    s4 = mfma32(K0, qf1, zero4);                            \
    s5 = mfma32(K1, qf1, zero4);                            \
    s6 = mfma32(K2, qf1, zero4);                            \
    s7 = mfma32(K3, qf1, zero4);                            \
    __builtin_amdgcn_s_setprio(0);                          \
    short8 p0, p1, p2, p3;                                  \
    PACKP(s0, s1, p0);                                      \
    PACKP(s2, s3, p1);                                      \
    PACKP(s4, s5, p2);                                      \
    PACKP(s6, s7, p3);                                      \
    __builtin_amdgcn_s_setprio(1);                          \
    o00 = mfma32(V0, p0, o00);                              \
    o01 = mfma32(V1, p1, o01);                              \
    o10 = mfma32(V0, p2, o10);                              \
    o11 = mfma32(V1, p3, o11);                              \
    __builtin_amdgcn_s_setprio(0);                          \
  } while (0)

  // software pipeline: 32 chunks of 64 keys; load i+1 before compute i
  LK(ka0, ka1, ka2, ka3); LV(va0, va1);
#pragma unroll 1
  for (int it = 0; it < 15; ++it) {
    LK(kb0, kb1, kb2, kb3); LV(vb0, vb1);
    COMPUTE(ka0, ka1, ka2, ka3, va0, va1);
    LK(ka0, ka1, ka2, ka3); LV(va0, va1);
    COMPUTE(kb0, kb1, kb2, kb3, vb0, vb1);
  }
  LK(kb0, kb1, kb2, kb3); LV(vb0, vb1);
  COMPUTE(ka0, ka1, ka2, ka3, va0, va1);
  COMPUTE(kb0, kb1, kb2, kb3, vb0, vb1);

#undef LK
#undef LV
#undef PACKP
#undef COMPUTE

  const f32x4 accA = o00 + o01;   // tile 0 (q0 + lm)
  const f32x4 accB = o10 + o11;   // tile 1 (q0 + 16 + lm)
  // row 8 (lane 32+lm, reg 0) holds sum(p) for q=lm
  const float invA = 1.0f / __shfl(accA[0], 32 + lm);
  const float invB = 1.0f / __shfl(accB[0], 32 + lm);

  // lane (lg<2, lm) holds O[d = lg*4 + r][q]
  if (lg < 2) {
    const size_t oA = (size_t)(b * SEQ + q0 + lm) * DIM + h * HD + lg * 4;
    *(uint32_t*)(attn_o + oA)     = pk2(accA[0] * invA, accA[1] * invA);
    *(uint32_t*)(attn_o + oA + 2) = pk2(accA[2] * invA, accA[3] * invA);
    const size_t oB = (size_t)(b * SEQ + q0 + 16 + lm) * DIM + h * HD + lg * 4;
    *(uint32_t*)(attn_o + oB)     = pk2(accB[0] * invB, accB[1] * invB);
    *(uint32_t*)(attn_o + oB + 2) = pk2(accB[2] * invB, accB[3] * invB);
  }
}

// ------------------------------------------------------------------
extern "C" void kernel_launch(void* const* d_in, const int* in_sizes, int n_in,
                              void* d_out, int out_size, void* d_ws, size_t ws_size,
                              hipStream_t stream) {
  const float* x  = (const float*)d_in[0];
  const float* wq = (const float*)d_in[1];
  const float* wk = (const float*)d_in[2];
  const float* wv = (const float*)d_in[3];
  const float* wo = (const float*)d_in[4];
  const float* w1 = (const float*)d_in[5];
  const float* w3 = (const float*)d_in[6];
  const float* w2 = (const float*)d_in[7];
  float* out = (float*)d_out;

  char* ws = (char*)d_ws;
  size_t off = 0;
  auto alloc = [&](size_t bytes) {
    size_t o = off;
    off += (bytes + 255) & ~(size_t)255;
    return o;
  };
  uint16_t* qkv_t  = (uint16_t*)(ws + alloc(384 * 128 * 2));
  uint16_t* wo_t   = (uint16_t*)(ws + alloc(128 * 128 * 2));
  uint16_t* w1_t   = (uint16_t*)(ws + alloc(384 * 128 * 2));
  uint16_t* w3_t   = (uint16_t*)(ws + alloc(384 * 128 * 2));
  uint16_t* w2_t   = (uint16_t*)(ws + alloc(128 * HIDP * 2));
  uint16_t* q_buf  = (uint16_t*)(ws + alloc((size_t)MROWS * DIM * 2));
  uint16_t* kc_b   = (uint16_t*)(ws + alloc((size_t)MROWS * DIM * 2));
  uint16_t* vt_b   = (uint16_t*)(ws + alloc((size_t)MROWS * DIM * 2));
  uint16_t* attn_o = (uint16_t*)(ws + alloc((size_t)MROWS * DIM * 2));
  uint16_t* h_bf   = (uint16_t*)(ws + alloc((size_t)MROWS * DIM * 2));
  uint16_t* u_buf  = (uint16_t*)(ws + alloc((size_t)MROWS * HIDP * 2));

  prep_kernel<<<512, 256, 0, stream>>>(wq, wk, wv, wo, w1, w3, w2,
                                       qkv_t, wo_t, w1_t, w3_t, w2_t);
  // qkv = x @ [wq*log2e | wk | wv] -> q_buf, Kc, Vt  (A read as fp32)
  rsgemm<0, 128, true><<<dim3(MROWS / 64, 6), 256, 0, stream>>>(
      x, qkv_t, nullptr, q_buf, nullptr, nullptr, kc_b, vt_b);
  // flash attention (no LDS, no barriers); 1024 blocks, 4/CU
  attn_kernel<<<dim3(BATCH * NH * (SEQ / 128)), 256, 0, stream>>>(
      q_buf, kc_b, vt_b, attn_o);
  // h = x + attn @ wo
  rsgemm<1, 128, false><<<dim3(MROWS / 64, 2), 256, 0, stream>>>(
      attn_o, wo_t, nullptr, h_bf, out, x, nullptr, nullptr);
  // u = silu(h@w1) * (h@w3)   (cols padded to 352 with zeros)
  rsgemm<2, 128, false><<<dim3(MROWS / 64, 6), 256, 0, stream>>>(
      h_bf, w1_t, w3_t, u_buf, nullptr, nullptr, nullptr, nullptr);
  // out += u @ w2
  rsgemm<3, HIDP, false><<<dim3(MROWS / 64, 2), 256, 0, stream>>>(
      u_buf, w2_t, nullptr, nullptr, out, nullptr, nullptr, nullptr);
}